// Round 8
// baseline (124351.672 us; speedup 1.0000x reference)
//
#include <hip/hip_runtime.h>
#include <math.h>

#define NNEUR 300          // NN
#define NFEAT 20           // NF
#define NPADN 320          // padded n-dimension (Wt rows)
#define MDIM  336          // m-dim: 300 r + 20 image + 1 hold + 1 const + 14 pad
#define NOUT  50
#define NPMAC 100          // NPM
#define TSTEPS 500
#define BATCH 1024
#define NTAIL 64           // tail rows 256..319 held in LDS

// Transposed augmented weights Wt[n][m] (NPADN x MDIM):
//   n<300: m<300 -> J[n][m]; m in [300,320) -> I[n][m-300];
//          m==320 -> S[n]; m==321 -> Bb[n]; else 0.   n>=300: 0.
__global__ void build_wt_kernel(const float* __restrict__ J,
                                const float* __restrict__ I,
                                const float* __restrict__ S,
                                const float* __restrict__ Bb,
                                float* __restrict__ Wt) {
    int e = blockIdx.x * 256 + threadIdx.x;
    if (e >= NPADN * MDIM) return;
    int n = e / MDIM, m = e % MDIM;
    float v = 0.0f;
    if (n < NNEUR) {
        if (m < NNEUR)                   v = J[n * NNEUR + m];
        else if (m < NNEUR + NFEAT)      v = I[n * NFEAT + (m - NNEUR)];
        else if (m == NNEUR + NFEAT)     v = S[n];
        else if (m == NNEUR + NFEAT + 1) v = Bb[n];
    }
    Wt[e] = v;
}

// Column-split persistent RNN: 256 blocks x 1024 threads (16 waves), 1 blk/CU.
// Lane owns output (n = tid>>2, b = tid&3), acc in 1 register chain (x4 comps).
// Tail outputs n in [256,320): 4 lanes split m, shuffle-reduce.
// raug double-buffered -> ONE barrier per step. W rows 0..255 streamed from L2
// (depth-6 float4 rotation, imm offsets); rows 256..319 in LDS.
__global__ __launch_bounds__(1024, 4) void rnn_kernel(
    const float* __restrict__ Wt,     // [NPADN][MDIM]
    const float* __restrict__ data,   // [T][21][B]
    const float* __restrict__ x0,     // [NNEUR]
    const float* __restrict__ fcw,    // [NOUT][NPMAC]
    const float* __restrict__ fcb,    // [NOUT]
    float* __restrict__ out)          // [T][B][NOUT]
{
    __shared__ __align__(16) float Wtl[NTAIL][MDIM];      // 86 KB: rows 256..319
    __shared__ __align__(16) float raug2[2][4][MDIM];     // 10.75 KB, dbuf [p][b][m]
    __shared__ float fcwt[NPMAC][NOUT];                   // 20 KB [p][o]
    __shared__ float fcbs[NOUT];

    const int tid = threadIdx.x;
    const int wid = tid >> 6;
    const int l   = tid & 63;
    const int b0  = blockIdx.x * 4;

    const int n  = tid >> 2;          // primary output row (0..255)
    const int b  = tid & 3;           // primary batch col
    const int n2 = 256 + 4 * wid + ((l >> 4) & 3);   // tail output row
    const int b2 = (l >> 2) & 3;
    const int mseg = l & 3;           // tail m-segment (21 float4 chunks each)

    // ---- init ----
    for (int i = tid; i < 2 * 4 * MDIM; i += 1024) ((float*)raug2)[i] = 0.0f;
    for (int i = tid; i < NPMAC * NOUT; i += 1024) {
        int p = i / NOUT, o = i - (i / NOUT) * NOUT;
        fcwt[p][o] = fcw[o * NPMAC + p];
    }
    if (tid < NOUT) fcbs[tid] = fcb[tid];
    for (int i = tid; i < NTAIL * MDIM; i += 1024)
        ((float*)Wtl)[i] = Wt[(size_t)256 * MDIM + i];
    __syncthreads();   // zeroing done before targeted writes below

    for (int i = tid; i < NNEUR; i += 1024) {
        float rv = fmaxf(tanhf(x0[i]), 0.0f);
        #pragma unroll
        for (int bb = 0; bb < 4; ++bb) raug2[0][bb][i] = rv;
    }
    if (tid < 8) raug2[tid >> 2][tid & 3][NNEUR + NFEAT + 1] = 1.0f;  // const row
    float4 dstage = make_float4(0.f, 0.f, 0.f, 0.f);
    if (tid < NFEAT + 1) {
        float4 d0 = *reinterpret_cast<const float4*>(data + (size_t)tid * BATCH + b0);
        raug2[0][0][NNEUR + tid] = d0.x; raug2[0][1][NNEUR + tid] = d0.y;
        raug2[0][2][NNEUR + tid] = d0.z; raug2[0][3][NNEUR + tid] = d0.w;
        dstage = *reinterpret_cast<const float4*>(
            data + ((size_t)(NFEAT + 1) + tid) * BATCH + b0);
    }

    float xs  = x0[n];                               // n < 256 always valid
    float xs2 = (n2 < NNEUR) ? x0[n2] : 0.0f;
    const float* Wrow = Wt + (size_t)n * MDIM;       // this lane's streamed row
    const float* Wt_l = &Wtl[4 * wid + ((l >> 4) & 3)][0];
    __syncthreads();

    int p = 0;
    for (int t = 0; t < TSTEPS; ++t) {
        const int q = p ^ 1;
        const float* rb  = &raug2[p][b][0];
        const float* rb2 = &raug2[p][b2][0];

        // ---- Phase B: primary dot (84 float4 chunks, depth-6 rotation) ----
        float4 u0, u1, u2, u3, u4, u5;
        float acc0 = 0.f, acc1 = 0.f, acc2 = 0.f, acc3 = 0.f;
#define LOADU(S, C) u##S = *reinterpret_cast<const float4*>(Wrow + 4 * (C));
        LOADU(0, 0) LOADU(1, 1) LOADU(2, 2) LOADU(3, 3) LOADU(4, 4) LOADU(5, 5)
#define PSTEP(C, S) { \
        const float4 rv_ = *reinterpret_cast<const float4*>(rb + 4 * (C)); \
        acc0 += u##S.x * rv_.x; acc1 += u##S.y * rv_.y; \
        acc2 += u##S.z * rv_.z; acc3 += u##S.w * rv_.w; \
        if ((C) + 6 < 84) { LOADU(S, (C) + 6) } }
#define G6(C0) PSTEP((C0)+0,0) PSTEP((C0)+1,1) PSTEP((C0)+2,2) \
               PSTEP((C0)+3,3) PSTEP((C0)+4,4) PSTEP((C0)+5,5)
        G6(0) G6(6) G6(12) G6(18) G6(24) G6(30) G6(36)
        G6(42) G6(48) G6(54) G6(60) G6(66) G6(72) G6(78)

        // ---- Phase B-tail: quarter-M dot from LDS, quad shuffle-reduce ----
        float ta0 = 0.f, ta1 = 0.f, ta2 = 0.f, ta3 = 0.f;
        {
            const int cbase = 21 * mseg;
            #pragma unroll 7
            for (int c = 0; c < 21; ++c) {
                const float4 wv_ = *reinterpret_cast<const float4*>(Wt_l + 4 * (cbase + c));
                const float4 rv_ = *reinterpret_cast<const float4*>(rb2 + 4 * (cbase + c));
                ta0 += wv_.x * rv_.x; ta1 += wv_.y * rv_.y;
                ta2 += wv_.z * rv_.z; ta3 += wv_.w * rv_.w;
            }
        }
        float tsum = (ta0 + ta1) + (ta2 + ta3);
        tsum += __shfl_xor(tsum, 1);
        tsum += __shfl_xor(tsum, 2);

        // ---- Phase C: in-register state update, write r into buffer q ----
        {
            float s = (acc0 + acc1) + (acc2 + acc3);
            float pre = xs + (s - xs) * 0.1f;
            xs = pre;
            raug2[q][b][n] = fmaxf(tanhf(pre), 0.0f);
            if (mseg == 0 && n2 < NNEUR) {
                float pre2 = xs2 + (tsum - xs2) * 0.1f;
                xs2 = pre2;
                raug2[q][b2][n2] = fmaxf(tanhf(pre2), 0.0f);
            }
        }

        // ---- Phase A: commit data[t+1] into buffer q, prefetch data[t+2] ----
        if (tid < NFEAT + 1 && t + 1 < TSTEPS) {
            raug2[q][0][NNEUR + tid] = dstage.x;
            raug2[q][1][NNEUR + tid] = dstage.y;
            raug2[q][2][NNEUR + tid] = dstage.z;
            raug2[q][3][NNEUR + tid] = dstage.w;
            if (t + 2 < TSTEPS)
                dstage = *reinterpret_cast<const float4*>(
                    data + ((size_t)(t + 2) * (NFEAT + 1) + tid) * BATCH + b0);
        }

        __syncthreads();   // the ONLY barrier: q complete; readers may proceed

        // ---- Phase D: y = r[:, :100] @ fcw.T + fcb  (reads buffer q) ----
        if (tid < 800) {
            int pair = tid >> 2, seg = tid & 3;
            int bD = pair / NOUT, oD = pair - (pair / NOUT) * NOUT;
            int pb = seg * 25;
            float y = 0.0f;
            #pragma unroll 5
            for (int k = 0; k < 25; ++k)
                y += raug2[q][bD][pb + k] * fcwt[pb + k][oD];
            y += __shfl_down(y, 1, 4);
            y += __shfl_down(y, 2, 4);
            if (seg == 0)
                out[((size_t)t * BATCH + b0 + bD) * NOUT + oD] = y + fcbs[oD];
        }
        // next C writes buffer p (old), which D/next-B (readers of q) never
        // touch; the per-step barrier already ordered B_t's reads of p.
        p = q;
    }
}

extern "C" void kernel_launch(void* const* d_in, const int* in_sizes, int n_in,
                              void* d_out, int out_size, void* d_ws, size_t ws_size,
                              hipStream_t stream) {
    const float* data = (const float*)d_in[0];
    const float* J    = (const float*)d_in[1];
    const float* I    = (const float*)d_in[2];
    const float* S    = (const float*)d_in[3];
    const float* Bb   = (const float*)d_in[4];
    const float* x0   = (const float*)d_in[5];
    const float* fcw  = (const float*)d_in[6];
    const float* fcb  = (const float*)d_in[7];
    float* out = (float*)d_out;
    float* Wt  = (float*)d_ws;   // NPADN*MDIM*4 = 430,080 bytes

    int wtot = NPADN * MDIM;
    build_wt_kernel<<<(wtot + 255) / 256, 256, 0, stream>>>(J, I, S, Bb, Wt);
    rnn_kernel<<<256, 1024, 0, stream>>>(Wt, data, x0, fcw, fcb, out);
}